// Round 3
// baseline (636.920 us; speedup 1.0000x reference)
//
#include <hip/hip_runtime.h>

// Graph WaveNet GCN on gfx950 — fused bf16 MFMA pipeline (prop+proj in one kernel).
// out[n,o,w,l] = b[o] + sum_{blk,c} W[o,blk*32+c] * H_blk[n,c,w,l]
//   H_0 = x,  H_{1+p} = x @ P_p over v,  P = [A0, A0^2, A1, A1^2, A2, A2^2]
//
// ws layout (bytes):
//   XT  @ 0         : Xt[(b*32+c)*13+l][v] bf16, 26624x512
//   BT  @ 27262976  : Bt[p][w][v] bf16 (P_p^T), 6 x 512x512
//   ABF @ 30408704  : A_s bf16 row-major, 3 x 512x512
//   WBF @ 31981568  : W bf16 [64][224]

typedef unsigned short u16;
typedef unsigned int   u32;
typedef __bf16 bf16x8 __attribute__((ext_vector_type(8)));
typedef float  f32x4  __attribute__((ext_vector_type(4)));

#define DEVI static __device__ __forceinline__

#define NB   64
#define NC   32
#define NV   512
#define NL   13
#define CO   64
#define CCAT 224
#define SZA  262144L        // 512*512

DEVI u16 f2bf(float f) {
  union { float f; u32 u; } v; v.f = f;
  u32 u = v.u;
  return (u16)((u + 0x7fffu + ((u >> 16) & 1u)) >> 16);  // RNE
}

DEVI void gl2lds16(const void* g, void* l) {
  __builtin_amdgcn_global_load_lds((__attribute__((address_space(1))) void*)g,
                                   (__attribute__((address_space(3))) void*)l, 16, 0, 0);
}

// ---------------------------------------------------------------- prep: supports
__global__ __launch_bounds__(256) void prep_A(const float* __restrict__ A0,
                                              const float* __restrict__ A1,
                                              const float* __restrict__ A2,
                                              u16* __restrict__ BT,
                                              u16* __restrict__ ABF) {
  const int s = blockIdx.z;
  const float* A = (s == 0) ? A0 : ((s == 1) ? A1 : A2);
  u16* abf = ABF + (long)s * SZA;
  u16* bt  = BT + (long)(2 * s) * SZA;
  __shared__ float t[32][33];
  const int v0 = blockIdx.x * 32, w0 = blockIdx.y * 32;
  const int tid = threadIdx.x;
  for (int i = tid; i < 1024; i += 256) {
    const int r = i >> 5, c = i & 31;
    const float val = A[(long)(v0 + r) * 512 + w0 + c];
    t[r][c] = val;
    abf[(long)(v0 + r) * 512 + w0 + c] = f2bf(val);
  }
  __syncthreads();
  for (int i = tid; i < 1024; i += 256) {
    const int r = i >> 5, c = i & 31;
    bt[(long)(w0 + r) * 512 + v0 + c] = f2bf(t[c][r]);
  }
}

// ---------------------------------------------------------------- prep: W -> bf16
__global__ __launch_bounds__(256) void prep_W(const float* __restrict__ W,
                                              u16* __restrict__ WBF) {
  const int i = blockIdx.x * 256 + threadIdx.x;
  WBF[i] = f2bf(W[i]);
}

// ---------------------------------------------------------------- transpose x
__global__ __launch_bounds__(256) void transpose_x(const float* __restrict__ x,
                                                   u16* __restrict__ XT) {
  __shared__ __align__(16) float tile[NV * NL];  // 26.6 KB
  const int bc = blockIdx.x;
  const float4* src4 = (const float4*)(x + (long)bc * (NV * NL));
  float4* t4 = (float4*)tile;
  for (int i = threadIdx.x; i < (NV * NL) / 4; i += 256) t4[i] = src4[i];
  __syncthreads();
  u16* dst = XT + (long)bc * (NL * NV);
  for (int j = threadIdx.x; j < NL * 256; j += 256) {
    const int l = j >> 8, v = (j & 255) * 2;
    const u32 lo = f2bf(tile[v * NL + l]);
    const u32 hi = f2bf(tile[(v + 1) * NL + l]);
    *(u32*)&dst[l * 512 + v] = lo | (hi << 16);
  }
}

// ---------------------------------------------------------------- small NT GEMM (A^2)
__global__ __launch_bounds__(256) void gemm512(const u16* __restrict__ Ag,
                                               const u16* __restrict__ Bg,
                                               u16* __restrict__ Cg,
                                               long aZ, long bZ, long cZ) {
  __shared__ u16 As[128 * 32];
  __shared__ u16 Bs[128 * 32];
  const int p = blockIdx.z;
  const u16* A = Ag + (long)p * aZ;
  const u16* B = Bg + (long)p * bZ;
  u16*       C = Cg + (long)p * cZ;
  const int m0 = blockIdx.y * 128, n0 = blockIdx.x * 128;
  const int tid = threadIdx.x;
  const int lane = tid & 63, wid = tid >> 6;
  const int wm = wid >> 1, wn = wid & 1;
  const int lr = lane & 15, lq = lane >> 4;
  const int srow = lane >> 2, skq = lane & 3;

  f32x4 acc[4][4] = {};

  for (int kt = 0; kt < 16; ++kt) {
    const int k0 = kt * 32;
    __syncthreads();
#pragma unroll
    for (int j = 0; j < 2; ++j) {
      const int rb = wid * 32 + j * 16;
      gl2lds16(A + (long)(m0 + rb + srow) * 512 + (k0 + skq * 8), &As[rb * 32]);
      gl2lds16(B + (long)(n0 + rb + srow) * 512 + (k0 + skq * 8), &Bs[rb * 32]);
    }
    __syncthreads();
    bf16x8 af[4], bv[4];
#pragma unroll
    for (int t = 0; t < 4; ++t) {
      af[t] = *(const bf16x8*)&As[(wm * 64 + t * 16 + lr) * 32 + lq * 8];
      bv[t] = *(const bf16x8*)&Bs[(wn * 64 + t * 16 + lr) * 32 + lq * 8];
    }
#pragma unroll
    for (int i = 0; i < 4; ++i)
#pragma unroll
      for (int j = 0; j < 4; ++j)
        acc[i][j] = __builtin_amdgcn_mfma_f32_16x16x32_bf16(af[i], bv[j], acc[i][j], 0, 0, 0);
  }
#pragma unroll
  for (int i = 0; i < 4; ++i) {
    const int mr = m0 + wm * 64 + i * 16 + lq * 4;
#pragma unroll
    for (int j = 0; j < 4; ++j) {
      const int nc = n0 + wn * 64 + j * 16 + lr;
#pragma unroll
      for (int r = 0; r < 4; ++r)
        C[(long)(mr + r) * 512 + nc] = f2bf(acc[i][j][r]);
    }
  }
}

// ---------------------------------------------------------------- fused prop + proj
// Block = (n, wch of 64 w). 512 threads / 8 waves. Per p: prop GEMM M=416,N=64,K=512
// with Y in regs (13 f32x4/thread), dump -> Hs[(w*13+l)][c] (stride 40), then 26
// proj MFMAs/wave accumulate out-tile (26 f32x4/thread). Triple-buffered k-staging
// with raw vmcnt(4)+s_barrier (one barrier per k-step, loads in flight across it).
__global__ __launch_bounds__(512, 2) void fused_gcn(const u16* __restrict__ Xt,
                                                    const u16* __restrict__ Bt,
                                                    const u16* __restrict__ WBF,
                                                    const float* __restrict__ bias,
                                                    float* __restrict__ out) {
  __shared__ u16 As[3][416 * 32];   // 3 x 26624 B
  __shared__ u16 Bs[3][64 * 32];    // 3 x  4096 B
  __shared__ u16 Hs[832 * 40];      //     66560 B   (total 158720 B)

  const int bid = blockIdx.x;
  const int n = bid >> 3, wch = bid & 7;
  const int tid = threadIdx.x, lane = tid & 63, wid = tid >> 6;
  const int lr = lane & 15, lq = lane >> 4;
  const int ot = wid >> 1, jpar = wid & 1;   // proj: o-tile, col-tile parity
  const int mt0 = wid >> 2, nt = wid & 3;    // prop: m-tile base, n(w)-tile
  const u16* XtN = Xt + (long)n * (416L * 512);

  f32x4 acco[26] = {};   // out tile: 26 (ot,jt) tiles of 16x16, 4 f32 each

  // stage(g): k-tile g&15 of p=g>>4 into buffer g%3. 32 gl2lds16 insts/block,
  // exactly 4 per wave (i=30,31 duplicate Bs rows 0-31: same src+dst, benign).
  auto stage = [&](int g) {
    const int p = g >> 4, kt = g & 15, bi = g % 3;
    const int rsub = lane >> 2, koff = kt * 32 + (lane & 3) * 8;
    const u16* Bp = Bt + (long)p * SZA + (long)(wch * 64) * 512;
#pragma unroll
    for (int t = 0; t < 4; ++t) {
      const int i = wid + t * 8;
      if (i < 26) {
        gl2lds16(XtN + (long)(i * 16 + rsub) * 512 + koff, &As[bi][i * 16 * 32]);
      } else {
        const int b = (i - 26) & 3;
        gl2lds16(Bp + (long)(b * 16 + rsub) * 512 + koff, &Bs[bi][b * 16 * 32]);
      }
    }
  };

  auto proj = [&](int blk) {
    const bf16x8 af = *(const bf16x8*)&WBF[(ot * 16 + lr) * CCAT + blk * 32 + lq * 8];
#pragma unroll
    for (int k = 0; k < 26; ++k) {
      const int jt = jpar + 2 * k;
      const bf16x8 bv = *(const bf16x8*)&Hs[(jt * 16 + lr) * 40 + lq * 8];
      acco[k] = __builtin_amdgcn_mfma_f32_16x16x32_bf16(af, bv, acco[k], 0, 0, 0);
    }
  };

  // prologue: issue stage(0) early, then stage Hs with x itself (blk 0)
  stage(0);
  for (int i = tid; i < 416 * 16; i += 512) {
    const int m = i >> 4, wq = i & 15;
    const ushort4 v = *(const ushort4*)(XtN + (long)m * 512 + wch * 64 + wq * 4);
    const int c = (m * 5042) >> 16, l = m - c * 13;  // m = c*13 + l
    const int rb = (wq * 4) * 13 + l;
    Hs[(rb +  0) * 40 + c] = v.x;
    Hs[(rb + 13) * 40 + c] = v.y;
    Hs[(rb + 26) * 40 + c] = v.z;
    Hs[(rb + 39) * 40 + c] = v.w;
  }
  __syncthreads();
  proj(0);

  for (int p = 0; p < 6; ++p) {
    f32x4 accp[13] = {};
    for (int kt = 0; kt < 16; ++kt) {
      const int g = p * 16 + kt;
      if (g < 95) {
        stage(g + 1);
        asm volatile("s_waitcnt vmcnt(4)\n\ts_barrier" ::: "memory");
      } else {
        asm volatile("s_waitcnt vmcnt(0)\n\ts_barrier" ::: "memory");
      }
      const u16* Ab = As[g % 3];
      const u16* Bb = Bs[g % 3];
      const bf16x8 bv = *(const bf16x8*)&Bb[(nt * 16 + lr) * 32 + lq * 8];
#pragma unroll
      for (int j = 0; j < 13; ++j) {
        const bf16x8 av = *(const bf16x8*)&Ab[((mt0 + 2 * j) * 16 + lr) * 32 + lq * 8];
        accp[j] = __builtin_amdgcn_mfma_f32_16x16x32_bf16(av, bv, accp[j], 0, 0, 0);
      }
    }
    // dump Y_p tile -> Hs[(w*13+l)][c]
#pragma unroll
    for (int j = 0; j < 13; ++j) {
      const int mt = mt0 + 2 * j;
#pragma unroll
      for (int r = 0; r < 4; ++r) {
        const int m = mt * 16 + lq * 4 + r;
        const int c = (m * 5042) >> 16, l = m - c * 13;
        Hs[((nt * 16 + lr) * 13 + l) * 40 + c] = f2bf(accp[j][r]);
      }
    }
    __syncthreads();
    proj(p + 1);
  }

  // epilogue: out[n][o][wch*64 + w][l], col j = w*13 + l contiguous
  float bia[4];
#pragma unroll
  for (int r = 0; r < 4; ++r) bia[r] = bias[ot * 16 + lq * 4 + r];
  const long obase = (long)n * (64L * 6656) + (long)wch * 832;
#pragma unroll
  for (int k = 0; k < 26; ++k) {
    const int j0 = (jpar + 2 * k) * 16;
#pragma unroll
    for (int r = 0; r < 4; ++r) {
      const int o = ot * 16 + lq * 4 + r;
      out[obase + (long)o * 6656 + j0 + lr] = acco[k][r] + bia[r];
    }
  }
}

extern "C" void kernel_launch(void* const* d_in, const int* in_sizes, int n_in,
                              void* d_out, int out_size, void* d_ws, size_t ws_size,
                              hipStream_t stream) {
  const float* x  = (const float*)d_in[0];
  const float* s0 = (const float*)d_in[1];
  const float* s1 = (const float*)d_in[2];
  const float* s2 = (const float*)d_in[3];
  const float* W  = (const float*)d_in[4];
  const float* b  = (const float*)d_in[5];
  float* out = (float*)d_out;

  char* ws = (char*)d_ws;
  u16* XT  = (u16*)(ws);
  u16* BT  = (u16*)(ws + 27262976L);
  u16* ABF = (u16*)(ws + 30408704L);
  u16* WBF = (u16*)(ws + 31981568L);

  prep_A<<<dim3(16, 16, 3), 256, 0, stream>>>(s0, s1, s2, BT, ABF);
  prep_W<<<dim3(56), 256, 0, stream>>>(W, WBF);
  // Bt[2s+1] = (A_s^2)^T = Bt[2s] (NT) ABF[s]
  gemm512<<<dim3(4, 4, 3), 256, 0, stream>>>(BT, ABF, BT + SZA,
                                             2L * SZA, 1L * SZA, 2L * SZA);
  transpose_x<<<dim3(NB * NC), 256, 0, stream>>>(x, XT);
  // fused propagation + projection; grid: bid = n*8 + wch
  fused_gcn<<<dim3(512), 512, 0, stream>>>(XT, BT, WBF, b, out);
}

// Round 4
// 411.211 us; speedup vs baseline: 1.5489x; 1.5489x over previous
//
#include <hip/hip_runtime.h>

// Graph WaveNet GCN on gfx950 — fused bf16 MFMA pipeline (prop+proj in one kernel).
// out[n,o,w,l] = b[o] + sum_{blk,c} W[o,blk*32+c] * H_blk[n,c,w,l]
//   H_0 = x,  H_{1+p} = x @ P_p over v,  P = [A0, A0^2, A1, A1^2, A2, A2^2]
//
// Fused kernel: block = (wch, n) with bid = wch*64 + n so the 8 same-n blocks
// share one XCD L2 (round-robin bid%8 = n%8). Per p-PAIR (2q, 2q+1): one K-pass
// (A-frag shared by both p's MFMAs), Y kept in regs, dumped to LDS Hs, projected.
//
// ws layout (bytes):
//   XT  @ 0         : Xt[(b*32+c)*13+l][v] bf16, 26624x512
//   BT  @ 27262976  : Bt[p][w][v] bf16 (P_p^T), 6 x 512x512
//   ABF @ 30408704  : A_s bf16 row-major, 3 x 512x512
//   WBF @ 31981568  : W bf16 [64][224]

typedef unsigned short u16;
typedef unsigned int   u32;
typedef __bf16 bf16x8 __attribute__((ext_vector_type(8)));
typedef float  f32x4  __attribute__((ext_vector_type(4)));

#define DEVI static __device__ __forceinline__

#define NB   64
#define NC   32
#define NV   512
#define NL   13
#define CO   64
#define CCAT 224
#define SZA  262144L        // 512*512

DEVI u16 f2bf(float f) {
  union { float f; u32 u; } v; v.f = f;
  u32 u = v.u;
  return (u16)((u + 0x7fffu + ((u >> 16) & 1u)) >> 16);  // RNE
}

DEVI void gl2lds16(const void* g, void* l) {
  __builtin_amdgcn_global_load_lds((__attribute__((address_space(1))) void*)g,
                                   (__attribute__((address_space(3))) void*)l, 16, 0, 0);
}

// ---------------------------------------------------------------- prep: supports
__global__ __launch_bounds__(256) void prep_A(const float* __restrict__ A0,
                                              const float* __restrict__ A1,
                                              const float* __restrict__ A2,
                                              u16* __restrict__ BT,
                                              u16* __restrict__ ABF) {
  const int s = blockIdx.z;
  const float* A = (s == 0) ? A0 : ((s == 1) ? A1 : A2);
  u16* abf = ABF + (long)s * SZA;
  u16* bt  = BT + (long)(2 * s) * SZA;
  __shared__ float t[32][33];
  const int v0 = blockIdx.x * 32, w0 = blockIdx.y * 32;
  const int tid = threadIdx.x;
  for (int i = tid; i < 1024; i += 256) {
    const int r = i >> 5, c = i & 31;
    const float val = A[(long)(v0 + r) * 512 + w0 + c];
    t[r][c] = val;
    abf[(long)(v0 + r) * 512 + w0 + c] = f2bf(val);
  }
  __syncthreads();
  for (int i = tid; i < 1024; i += 256) {
    const int r = i >> 5, c = i & 31;
    bt[(long)(w0 + r) * 512 + v0 + c] = f2bf(t[c][r]);
  }
}

// ---------------------------------------------------------------- prep: W -> bf16
__global__ __launch_bounds__(256) void prep_W(const float* __restrict__ W,
                                              u16* __restrict__ WBF) {
  const int i = blockIdx.x * 256 + threadIdx.x;
  WBF[i] = f2bf(W[i]);
}

// ---------------------------------------------------------------- transpose x
__global__ __launch_bounds__(256) void transpose_x(const float* __restrict__ x,
                                                   u16* __restrict__ XT) {
  __shared__ __align__(16) float tile[NV * NL];  // 26.6 KB
  const int bc = blockIdx.x;
  const float4* src4 = (const float4*)(x + (long)bc * (NV * NL));
  float4* t4 = (float4*)tile;
  for (int i = threadIdx.x; i < (NV * NL) / 4; i += 256) t4[i] = src4[i];
  __syncthreads();
  u16* dst = XT + (long)bc * (NL * NV);
  for (int j = threadIdx.x; j < NL * 256; j += 256) {
    const int l = j >> 8, v = (j & 255) * 2;
    const u32 lo = f2bf(tile[v * NL + l]);
    const u32 hi = f2bf(tile[(v + 1) * NL + l]);
    *(u32*)&dst[l * 512 + v] = lo | (hi << 16);
  }
}

// ---------------------------------------------------------------- small NT GEMM (A^2)
__global__ __launch_bounds__(256) void gemm512(const u16* __restrict__ Ag,
                                               const u16* __restrict__ Bg,
                                               u16* __restrict__ Cg,
                                               long aZ, long bZ, long cZ) {
  __shared__ u16 As[128 * 32];
  __shared__ u16 Bs[128 * 32];
  const int p = blockIdx.z;
  const u16* A = Ag + (long)p * aZ;
  const u16* B = Bg + (long)p * bZ;
  u16*       C = Cg + (long)p * cZ;
  const int m0 = blockIdx.y * 128, n0 = blockIdx.x * 128;
  const int tid = threadIdx.x;
  const int lane = tid & 63, wid = tid >> 6;
  const int wm = wid >> 1, wn = wid & 1;
  const int lr = lane & 15, lq = lane >> 4;
  const int srow = lane >> 2, skq = lane & 3;

  f32x4 acc[4][4] = {};

  for (int kt = 0; kt < 16; ++kt) {
    const int k0 = kt * 32;
    __syncthreads();
#pragma unroll
    for (int j = 0; j < 2; ++j) {
      const int rb = wid * 32 + j * 16;
      gl2lds16(A + (long)(m0 + rb + srow) * 512 + (k0 + skq * 8), &As[rb * 32]);
      gl2lds16(B + (long)(n0 + rb + srow) * 512 + (k0 + skq * 8), &Bs[rb * 32]);
    }
    __syncthreads();
    bf16x8 af[4], bv[4];
#pragma unroll
    for (int t = 0; t < 4; ++t) {
      af[t] = *(const bf16x8*)&As[(wm * 64 + t * 16 + lr) * 32 + lq * 8];
      bv[t] = *(const bf16x8*)&Bs[(wn * 64 + t * 16 + lr) * 32 + lq * 8];
    }
#pragma unroll
    for (int i = 0; i < 4; ++i)
#pragma unroll
      for (int j = 0; j < 4; ++j)
        acc[i][j] = __builtin_amdgcn_mfma_f32_16x16x32_bf16(af[i], bv[j], acc[i][j], 0, 0, 0);
  }
#pragma unroll
  for (int i = 0; i < 4; ++i) {
    const int mr = m0 + wm * 64 + i * 16 + lq * 4;
#pragma unroll
    for (int j = 0; j < 4; ++j) {
      const int nc = n0 + wn * 64 + j * 16 + lr;
#pragma unroll
      for (int r = 0; r < 4; ++r)
        C[(long)(mr + r) * 512 + nc] = f2bf(acc[i][j][r]);
    }
  }
}

// ---------------------------------------------------------------- fused prop + proj
// 512 threads / 8 waves, 1 block/CU (133 KB LDS). Prop per pair: M=416,N=64,K=512,
// A-frag shared by the pair's two MFMAs. Double-buffered staging; stage(g+1) is
// issued AFTER the k-step barrier so __syncthreads' vmcnt(0) drain only waits on
// loads issued a full k-step earlier (free) and the 2-buffer overwrite is race-free.
__global__ __launch_bounds__(512, 2) void fused_gcn(const u16* __restrict__ Xt,
                                                    const u16* __restrict__ Bt,
                                                    const u16* __restrict__ WBF,
                                                    const float* __restrict__ bias,
                                                    float* __restrict__ out) {
  __shared__ u16 As[2][416 * 32];     // 2 x 26624 B
  __shared__ u16 Bs[2][2][64 * 32];   // 2 x 2 x 4096 B
  __shared__ u16 Hs[832 * 40];        // 66560 B  (total 136192 B)

  const int bid = blockIdx.x;
  const int wch = bid >> 6, n = bid & 63;    // XCD = bid%8 = n%8 -> same-n co-located
  const int tid = threadIdx.x, lane = tid & 63, wid = tid >> 6;
  const int lr = lane & 15, lq = lane >> 4;
  const int mt0 = wid >> 2, nt = wid & 3;    // prop roles
  const int ot2 = wid & 1, j4 = wid >> 1;    // proj roles: o-tiles {ot2,ot2+2}, jt [j4*13,+13)
  const u16* XtN = Xt + (long)n * (416L * 512);

  f32x4 acco[26] = {};      // proj out tile: (k13, oi) -> acco[k13*2+oi]
  f32x4 accp[2][13];        // prop Y for the p-pair

  auto stage = [&](int g) {  // k-tile g&15 of pair g>>4 into buffer g&1
    const int q = g >> 4, kt = g & 15, bi = g & 1;
    const int rsub = lane >> 2, koff = kt * 32 + (lane & 3) * 8;
    const u16* Bp = Bt + (long)(2 * q) * SZA + (long)(wch * 64) * 512;
#pragma unroll
    for (int t = 0; t < 5; ++t) {
      const int i = wid + t * 8;
      if (i < 26) {
        gl2lds16(XtN + (long)(i * 16 + rsub) * 512 + koff, &As[bi][i * 512]);
      } else if (i < 34) {
        const int idx = i - 26, pi = idx >> 2, b = idx & 3;
        gl2lds16(Bp + (long)pi * SZA + (long)(b * 16 + rsub) * 512 + koff,
                 &Bs[bi][pi][b * 512]);
      }
    }
  };

  auto proj = [&](int blk) {
    bf16x8 af[2];
#pragma unroll
    for (int oi = 0; oi < 2; ++oi)
      af[oi] = *(const bf16x8*)&WBF[((ot2 + 2 * oi) * 16 + lr) * CCAT + blk * 32 + lq * 8];
#pragma unroll
    for (int k = 0; k < 13; ++k) {
      const int jt = j4 * 13 + k;
      const bf16x8 bv = *(const bf16x8*)&Hs[(jt * 16 + lr) * 40 + lq * 8];
      acco[k * 2 + 0] = __builtin_amdgcn_mfma_f32_16x16x32_bf16(af[0], bv, acco[k * 2 + 0], 0, 0, 0);
      acco[k * 2 + 1] = __builtin_amdgcn_mfma_f32_16x16x32_bf16(af[1], bv, acco[k * 2 + 1], 0, 0, 0);
    }
  };

  // prologue: stage(0) early, then Hs = x block (blk 0) straight from global
  stage(0);
  for (int i = tid; i < 416 * 16; i += 512) {   // 13 iters exact
    const int m = i >> 4, wq = i & 15;
    const ushort4 v = *(const ushort4*)(XtN + (long)m * 512 + wch * 64 + wq * 4);
    const int c = (m * 5042) >> 16, l = m - c * 13;
    const int rb = (wq * 4) * 13 + l;
    Hs[(rb +  0) * 40 + c] = v.x;
    Hs[(rb + 13) * 40 + c] = v.y;
    Hs[(rb + 26) * 40 + c] = v.z;
    Hs[(rb + 39) * 40 + c] = v.w;
  }
  __syncthreads();
  proj(0);

  for (int q = 0; q < 3; ++q) {
#pragma unroll
    for (int pi = 0; pi < 2; ++pi)
#pragma unroll
      for (int j = 0; j < 13; ++j) accp[pi][j] = f32x4{0.f, 0.f, 0.f, 0.f};

    for (int kt = 0; kt < 16; ++kt) {
      const int g = q * 16 + kt, bi = g & 1;
      __syncthreads();               // drains stage(g) (issued one k-step ago: free)
      if (g < 47) stage(g + 1);      // in flight across next barrier
      const bf16x8 bv0 = *(const bf16x8*)&Bs[bi][0][(nt * 16 + lr) * 32 + lq * 8];
      const bf16x8 bv1 = *(const bf16x8*)&Bs[bi][1][(nt * 16 + lr) * 32 + lq * 8];
#pragma unroll
      for (int j = 0; j < 13; ++j) {
        const bf16x8 av = *(const bf16x8*)&As[bi][((mt0 + 2 * j) * 16 + lr) * 32 + lq * 8];
        accp[0][j] = __builtin_amdgcn_mfma_f32_16x16x32_bf16(av, bv0, accp[0][j], 0, 0, 0);
        accp[1][j] = __builtin_amdgcn_mfma_f32_16x16x32_bf16(av, bv1, accp[1][j], 0, 0, 0);
      }
    }
#pragma unroll
    for (int pi = 0; pi < 2; ++pi) {
      __syncthreads();               // prev Hs readers done
      // dump Y(p = 2q+pi): lane holds col w_local = nt*16+lr, rows m
#pragma unroll
      for (int j = 0; j < 13; ++j) {
#pragma unroll
        for (int r = 0; r < 4; ++r) {
          const int m = (mt0 + 2 * j) * 16 + lq * 4 + r;
          const int c = (m * 5042) >> 16, l = m - c * 13;
          Hs[((nt * 16 + lr) * 13 + l) * 40 + c] = f2bf(accp[pi][j][r]);
        }
      }
      __syncthreads();
      proj(1 + 2 * q + pi);
    }
  }

  // epilogue: out[n][o][w][l]; col j = w*13+l contiguous per o-row
  float bia[2][4];
#pragma unroll
  for (int oi = 0; oi < 2; ++oi)
#pragma unroll
    for (int r = 0; r < 4; ++r) bia[oi][r] = bias[(ot2 + 2 * oi) * 16 + lq * 4 + r];
  const long obase = (long)n * (64L * 6656) + (long)wch * 832;
#pragma unroll
  for (int k = 0; k < 13; ++k) {
    const int j0 = (j4 * 13 + k) * 16;
#pragma unroll
    for (int oi = 0; oi < 2; ++oi) {
#pragma unroll
      for (int r = 0; r < 4; ++r) {
        const int o = (ot2 + 2 * oi) * 16 + lq * 4 + r;
        out[obase + (long)o * 6656 + j0 + lr] = acco[k * 2 + oi][r] + bia[oi][r];
      }
    }
  }
}

extern "C" void kernel_launch(void* const* d_in, const int* in_sizes, int n_in,
                              void* d_out, int out_size, void* d_ws, size_t ws_size,
                              hipStream_t stream) {
  const float* x  = (const float*)d_in[0];
  const float* s0 = (const float*)d_in[1];
  const float* s1 = (const float*)d_in[2];
  const float* s2 = (const float*)d_in[3];
  const float* W  = (const float*)d_in[4];
  const float* b  = (const float*)d_in[5];
  float* out = (float*)d_out;

  char* ws = (char*)d_ws;
  u16* XT  = (u16*)(ws);
  u16* BT  = (u16*)(ws + 27262976L);
  u16* ABF = (u16*)(ws + 30408704L);
  u16* WBF = (u16*)(ws + 31981568L);

  prep_A<<<dim3(16, 16, 3), 256, 0, stream>>>(s0, s1, s2, BT, ABF);
  prep_W<<<dim3(56), 256, 0, stream>>>(W, WBF);
  // Bt[2s+1] = (A_s^2)^T = Bt[2s] (NT) ABF[s]
  gemm512<<<dim3(4, 4, 3), 256, 0, stream>>>(BT, ABF, BT + SZA,
                                             2L * SZA, 1L * SZA, 2L * SZA);
  transpose_x<<<dim3(NB * NC), 256, 0, stream>>>(x, XT);
  // fused propagation + projection; bid = wch*64 + n (same-n blocks -> same XCD)
  fused_gcn<<<dim3(512), 512, 0, stream>>>(XT, BT, WBF, b, out);
}